// Round 11
// baseline (1870.334 us; speedup 1.0000x reference)
//
#include <hip/hip_runtime.h>

#define TT   512
#define IDIM 64
#define HDIM 256

typedef short  short8  __attribute__((ext_vector_type(8)));
typedef short  short4v __attribute__((ext_vector_type(4)));
typedef float  f32x4   __attribute__((ext_vector_type(4)));
typedef unsigned long long u64;

__device__ __forceinline__ short f2bf(float f) {
    unsigned u = __float_as_uint(f);
    u = u + 0x7FFFu + ((u >> 16) & 1u);   // round-to-nearest-even
    return (short)(u >> 16);
}
__device__ __forceinline__ float bf2f(short h) {
    return __uint_as_float(((unsigned)(unsigned short)h) << 16);
}
__device__ __forceinline__ float sigm(float x)  { return 1.0f / (1.0f + __expf(-x)); }
__device__ __forceinline__ float tanh_(float x) { return 2.0f / (1.0f + __expf(-2.0f * x)) - 1.0f; }

// Unpack 16 bf16 units from 6 seq-tagged words (h1 path, r10 format)
__device__ __forceinline__ void unpack16(const u64 W[6], u64 q[4]) {
    unsigned short u[16];
#pragma unroll
    for (int w = 0; w < 6; ++w)
#pragma unroll
        for (int k = 0; k < 3; ++k) {
            int j = 3 * w + k;
            if (j < 16) u[j] = (unsigned short)(W[w] >> (16 * k));
        }
#pragma unroll
    for (int t = 0; t < 4; ++t)
        q[t] = (u64)u[4*t] | ((u64)u[4*t+1] << 16) | ((u64)u[4*t+2] << 32) | ((u64)u[4*t+3] << 48);
}

// 256 persistent workgroups = 16 batch-groups (grp, 16 rows) x 16 hidden-chunks.
// r10 structure (split poll: h0 phase3-publish/phase8-poll; h1[s-2] phase3-poll,
// phase6-publish) with ONE change — h0's exchange is decongested:
//   * h0 data: plain-packed 4-unit u64 words (4 swaps/row), NO inline tags.
//   * h0 tag: one u64 per (row,chunk), swapped AFTER wave-level vmcnt(0) acks
//     the data swaps. Non-returning agent atomics ack from the MALL execution
//     point (r2 disproved this only for PLAIN stores), so tag-visible =>
//     data-swaps-executed.
//   * reader polls ONLY its 8B tag (16 tags/row = 2 coalesced lines: ~8x less
//     repoll traffic/round than rereading 48B data) then fetches 32B data ONCE,
//     issued strictly after detect (compiler barrier; issued-after-completion
//     => serviced after the already-executed data swaps).
// Rationale: r1/r8/r10 all show the poll traffic itself congests the MALL and
// delays the publishes being polled. Cut round traffic ~8x, pay one post-detect
// RT. h1 path and everything else: r10 bit-for-bit. Budgets => hang-proof.
__global__ __launch_bounds__(256, 1) void lstm_fused(
    const float* __restrict__ x,
    const float* __restrict__ Wih0, const float* __restrict__ Whh0,
    const float* __restrict__ bih0, const float* __restrict__ bhh0,
    const float* __restrict__ Wih1, const float* __restrict__ Whh1,
    const float* __restrict__ bih1, const float* __restrict__ bhh1,
    const float* __restrict__ Wfc,  const float* __restrict__ bfc,
    float* __restrict__ out, char* __restrict__ ws)
{
    u64* h0dat = (u64*)ws;                    // [2][16][16][64] packed 4-unit words
    u64* h0tag = h0dat + 2 * 16 * 16 * 64;    // [2][16][16][16] one tag per (row,chunk)
    u64* h1buf = h0tag + 2 * 16 * 16 * 16;    // [2][16][16][96] r10 seq-tagged words
    // total = 704 KiB (< proven 1 MiB ws capacity)

    const int blk   = blockIdx.x;
    const int grp   = ((blk & 7) << 1) | ((blk >> 3) & 1); // batch-group 0..15
    const int chunk = blk >> 4;                            // hidden-chunk 0..15
    const int tid   = threadIdx.x;
    const int lane  = tid & 63;
    const int wave  = tid >> 6;      // gate index: 0=i 1=f 2=g 3=o
    const int quad  = lane >> 4;
    const int nn    = lane & 15;     // W-row within 16-row tile

    __shared__ short A0[16][328];    // [m][ x(64) | h0(256) ] + pad
    __shared__ short A1[16][520];    // [m][ h0(256) | h1(256) ] + pad
    __shared__ float gbuf[2][4][16][17];  // row pad: de-alias gate-write banks
    __shared__ float red[16][16];
    __shared__ float ldspad[5120];   // occupancy limiter: ~57 KB -> 1 wg/CU

    // zero A buffers (h0[-1] = 0, h1[-1] = 0 for the s==1 layer1 step)
    for (int i = tid; i < 16 * 328; i += 256) (&A0[0][0])[i] = 0;
    for (int i = tid; i < 16 * 520; i += 256) (&A1[0][0])[i] = 0;

    // ---- static weight fragments -> registers (B operand: W[n][k], n=lane&15, k=quad*8+j)
    const int wrow = wave * HDIM + chunk * 16 + nn;
    short8 w0f[10];   // layer0: kb 0..1 = Wih0 (K 0..63), kb 2..9 = Whh0 (K 64..319)
    short8 w1f[16];   // layer1: kb 0..7 = Wih1 (K 0..255), kb 8..15 = Whh1 (K 256..511)
#pragma unroll
    for (int kb = 0; kb < 10; ++kb)
#pragma unroll
        for (int j = 0; j < 8; ++j) {
            int k = kb * 32 + quad * 8 + j;
            float v = (k < 64) ? Wih0[wrow * IDIM + k] : Whh0[wrow * HDIM + (k - 64)];
            w0f[kb][j] = f2bf(v);
        }
#pragma unroll
    for (int kb = 0; kb < 16; ++kb)
#pragma unroll
        for (int j = 0; j < 8; ++j) {
            int k = kb * 32 + quad * 8 + j;
            float v = (k < 256) ? Wih1[wrow * HDIM + k] : Whh1[wrow * HDIM + (k - 256)];
            w1f[kb][j] = f2bf(v);
        }
    const float bias0 = bih0[wrow] + bhh0[wrow];
    const float bias1 = bih1[wrow] + bhh1[wrow];

    const int em = tid >> 4;   // elementwise batch row (0..15)
    const int ej = tid & 15;   // elementwise hidden unit within chunk / gather chunk
    float c0 = 0.0f, c1 = 0.0f;

    auto load_x = [&](int t) {
        const float4 v = *(const float4*)&x[((size_t)(grp * 16 + em) * TT + t) * IDIM + ej * 4];
        short4v sv;
        sv[0] = f2bf(v.x); sv[1] = f2bf(v.y); sv[2] = f2bf(v.z); sv[3] = f2bf(v.w);
        *(short4v*)&A0[em][ej * 4] = sv;
    };

    __syncthreads();
    load_x(0);
    __syncthreads();

    // super-step s: layer0 computes h0[s] (s<T); layer1 computes h1[s-1] (s>=1)
    for (int s = 0; s <= TT; ++s) {
        // ---- phase 1: MFMA0 (layer0 gates from A0 = [x[s] | h0[s-1]])
        if (s < TT) {
            f32x4 accA = {0.f, 0.f, 0.f, 0.f}, accB = {0.f, 0.f, 0.f, 0.f};
#pragma unroll
            for (int kb = 0; kb < 10; kb += 2) {   // 2 chains: halve dep latency
                short8 a0v = *(const short8*)&A0[nn][kb * 32 + quad * 8];
                short8 a1v = *(const short8*)&A0[nn][(kb + 1) * 32 + quad * 8];
                accA = __builtin_amdgcn_mfma_f32_16x16x32_bf16(a0v, w0f[kb],     accA, 0, 0, 0);
                accB = __builtin_amdgcn_mfma_f32_16x16x32_bf16(a1v, w0f[kb + 1], accB, 0, 0, 0);
            }
            const f32x4 acc = accA + accB;
#pragma unroll
            for (int r = 0; r < 4; ++r)
                gbuf[0][wave][quad * 4 + r][nn] = acc[r] + bias0;
        }
        __syncthreads();   // bar1: gbuf0 complete

        // ---- phase 3: issue h1[s-2] poll loads -> cell0 -> publish h0 data ->
        //      vmcnt -> publish h0 tag -> check/gather h1
        {
            const bool gh1 = (s >= 2);
            const unsigned sq1 = (unsigned)s;   // tag of h1[s-2] (published step s-1)
            const size_t rb1 = (((size_t)((s - 1) & 1) * 16 + grp) * 16 + em) * 96 + ej * 6;
            u64 W1[6];
            if (gh1) {
#pragma unroll
                for (int i = 0; i < 6; ++i)     // issue early; fly under cell0
                    W1[i] = __hip_atomic_load(&h1buf[rb1 + i],
                                              __ATOMIC_RELAXED, __HIP_MEMORY_SCOPE_AGENT);
            }

            if (s < TT) {
                float gi = sigm (gbuf[0][0][em][ej]);
                float gf = sigm (gbuf[0][1][em][ej]);
                float gg = tanh_(gbuf[0][2][em][ej]);
                float go = sigm (gbuf[0][3][em][ej]);
                c0 = gf * c0 + gi * gg;
                const short h0v = f2bf(go * tanh_(c0));
                const int hv = (int)(unsigned short)h0v;
                const int n1 = __shfl_down(hv, 1);
                const int n2 = __shfl_down(hv, 2);
                const int n3 = __shfl_down(hv, 3);
                if ((ej & 3) == 0) {            // 4 data words per row, plain-packed
                    u64 d = (u64)(unsigned)(hv & 0xFFFF)
                          | ((u64)(unsigned)(n1 & 0xFFFF) << 16)
                          | ((u64)(unsigned)(n2 & 0xFFFF) << 32)
                          | ((u64)(unsigned)(n3 & 0xFFFF) << 48);
                    const size_t di = (((size_t)(s & 1) * 16 + grp) * 16 + em) * 64
                                      + chunk * 4 + (ej >> 2);
                    (void)__hip_atomic_exchange(&h0dat[di], d,
                                                __ATOMIC_RELAXED, __HIP_MEMORY_SCOPE_AGENT);
                }
            }
            // wave-level ack: data swaps MALL-executed (also drains W1 loads)
            asm volatile("s_waitcnt vmcnt(0)" ::: "memory");
            if (s < TT && ej == 0) {
                const size_t ti = (((size_t)(s & 1) * 16 + grp) * 16 + em) * 16 + chunk;
                (void)__hip_atomic_exchange(&h0tag[ti], (u64)(unsigned)(s + 1),
                                            __ATOMIC_RELAXED, __HIP_MEMORY_SCOPE_AGENT);
            }

            if (gh1) {
                bool ok = true;
#pragma unroll
                for (int i = 0; i < 6; ++i) ok &= ((unsigned)(W1[i] >> 48) == sq1);
                int budget = 1 << 17;   // expected: already visible -> no spin
                while (!ok && budget-- > 0) {
#pragma unroll
                    for (int i = 0; i < 6; ++i)
                        W1[i] = __hip_atomic_load(&h1buf[rb1 + i],
                                                  __ATOMIC_RELAXED, __HIP_MEMORY_SCOPE_AGENT);
                    ok = true;
#pragma unroll
                    for (int i = 0; i < 6; ++i) ok &= ((unsigned)(W1[i] >> 48) == sq1);
                }
                u64 q[4]; unpack16(W1, q);
                u64* d2 = (u64*)&A1[em][256 + ej * 16];
#pragma unroll
                for (int t = 0; t < 4; ++t) d2[t] = q[t];
            }
        }
        __syncthreads();   // bar1.5: A1 h1-region ready for MFMA1

        // ---- phase 4: MFMA1 (A1 = [h0[s-1] | h1[s-2]]) inside h0's visibility window
        if (s >= 1) {
            f32x4 accA = {0.f, 0.f, 0.f, 0.f}, accB = {0.f, 0.f, 0.f, 0.f};
#pragma unroll
            for (int kb = 0; kb < 16; kb += 2) {
                short8 a0v = *(const short8*)&A1[nn][kb * 32 + quad * 8];
                short8 a1v = *(const short8*)&A1[nn][(kb + 1) * 32 + quad * 8];
                accA = __builtin_amdgcn_mfma_f32_16x16x32_bf16(a0v, w1f[kb],     accA, 0, 0, 0);
                accB = __builtin_amdgcn_mfma_f32_16x16x32_bf16(a1v, w1f[kb + 1], accB, 0, 0, 0);
            }
            const f32x4 acc = accA + accB;
#pragma unroll
            for (int r = 0; r < 4; ++r)
                gbuf[1][wave][quad * 4 + r][nn] = acc[r] + bias1;
        }
        __syncthreads();   // bar2: gbuf1 complete; all MFMA1 A1-reads done

        // ---- phase 6: cell1 + publish h1[s-1] (r10 per-word-tag format, proven)
        {
            short h1v = 0;
            if (s >= 1) {
                float gi = sigm (gbuf[1][0][em][ej]);
                float gf = sigm (gbuf[1][1][em][ej]);
                float gg = tanh_(gbuf[1][2][em][ej]);
                float go = sigm (gbuf[1][3][em][ej]);
                c1 = gf * c1 + gi * gg;
                h1v = f2bf(go * tanh_(c1));
            }
            const int hv = (int)(unsigned short)h1v;
            const int n1 = __shfl_down(hv, 1);
            const int n2 = __shfl_down(hv, 2);
            if ((ej % 3) == 0) {
                const int w = ej / 3;
                u64 v1 = (u64)(unsigned)(s + 1) << 48;
                v1 |= (u64)(unsigned)(hv & 0xFFFF);
                if (w < 5) {
                    v1 |= (u64)(unsigned)(n1 & 0xFFFF) << 16;
                    v1 |= (u64)(unsigned)(n2 & 0xFFFF) << 32;
                }
                const size_t base = (((size_t)(s & 1) * 16 + grp) * 16 + em) * 96
                                    + chunk * 6 + w;
                (void)__hip_atomic_exchange(&h1buf[base], v1,
                                            __ATOMIC_RELAXED, __HIP_MEMORY_SCOPE_AGENT);
            }
        }

        if (s + 1 < TT) load_x(s + 1);   // overlap x prefetch with the poll

        // ---- phase 8: poll h0 TAG (8B/round) -> fetch 32B data once
        {
            const bool g0 = (s < TT);
            if (g0) {
                const u64 sq = (u64)(unsigned)(s + 1);
                const size_t ti = (((size_t)(s & 1) * 16 + grp) * 16 + em) * 16 + ej;
                u64 t;
                int budget = 1 << 17;   // hang-proofing
                do {
                    t = __hip_atomic_load(&h0tag[ti],
                                          __ATOMIC_RELAXED, __HIP_MEMORY_SCOPE_AGENT);
                } while (t != sq && budget-- > 0);
                asm volatile("" ::: "memory");   // data loads must ISSUE after detect

                const size_t di = (((size_t)(s & 1) * 16 + grp) * 16 + em) * 64 + ej * 4;
                const u64 q0 = __hip_atomic_load(&h0dat[di + 0],
                                                 __ATOMIC_RELAXED, __HIP_MEMORY_SCOPE_AGENT);
                const u64 q1 = __hip_atomic_load(&h0dat[di + 1],
                                                 __ATOMIC_RELAXED, __HIP_MEMORY_SCOPE_AGENT);
                const u64 q2 = __hip_atomic_load(&h0dat[di + 2],
                                                 __ATOMIC_RELAXED, __HIP_MEMORY_SCOPE_AGENT);
                const u64 q3 = __hip_atomic_load(&h0dat[di + 3],
                                                 __ATOMIC_RELAXED, __HIP_MEMORY_SCOPE_AGENT);
                u64* d0 = (u64*)&A0[em][64 + ej * 16];
                u64* d1 = (u64*)&A1[em][ej * 16];
                d0[0] = q0; d0[1] = q1; d0[2] = q2; d0[3] = q3;
                d1[0] = q0; d1[1] = q1; d1[2] = q2; d1[3] = q3;
            }
            // drain: publishes/polls retired before next region reuse
            asm volatile("s_waitcnt vmcnt(0)" ::: "memory");
        }
        __syncthreads();   // bar3
    }

    // ---- final: gather h1[T-1] (published step TT, tag TT+1, region TT&1)
    {
        const unsigned sq = (unsigned)(TT + 1);
        const size_t rb = (((size_t)(TT & 1) * 16 + grp) * 16 + em) * 96 + ej * 6;
        u64 W1[6];
        bool ok = false;
        int budget = 1 << 17;
        do {
#pragma unroll
            for (int i = 0; i < 6; ++i)
                W1[i] = __hip_atomic_load(&h1buf[rb + i],
                                          __ATOMIC_RELAXED, __HIP_MEMORY_SCOPE_AGENT);
            ok = true;
#pragma unroll
            for (int i = 0; i < 6; ++i) ok &= ((unsigned)(W1[i] >> 48) == sq);
        } while (!ok && budget-- > 0);
        u64 q[4]; unpack16(W1, q);
        u64* d2 = (u64*)&A1[em][256 + ej * 16];
#pragma unroll
        for (int t = 0; t < 4; ++t) d2[t] = q[t];
    }
    __syncthreads();

    // FC epilogue: A1[:,256..511] holds h1[T-1] (bf16)
    {
        float part = 0.f;
#pragma unroll
        for (int kk = 0; kk < 16; ++kk) {
            int k = ej * 16 + kk;
            part += bf2f(A1[em][256 + k]) * Wfc[k];
        }
        red[em][ej] = part;
    }
    __syncthreads();
    if (chunk == 0 && tid < 16) {
        float sum = bfc[0];
#pragma unroll
        for (int c = 0; c < 16; ++c) sum += red[tid][c];
        out[grp * 16 + tid] = sum;
    }

    // keep ldspad allocated (occupancy cap); never true at runtime
    if (gridDim.x > 100000) { ldspad[tid] = bias0; out[0] = ldspad[255 - tid]; }
}

extern "C" void kernel_launch(void* const* d_in, const int* in_sizes, int n_in,
                              void* d_out, int out_size, void* d_ws, size_t ws_size,
                              hipStream_t stream) {
    (void)in_sizes; (void)n_in; (void)out_size; (void)ws_size;
    const float* x    = (const float*)d_in[0];
    const float* Wih0 = (const float*)d_in[1];
    const float* Whh0 = (const float*)d_in[2];
    const float* bih0 = (const float*)d_in[3];
    const float* bhh0 = (const float*)d_in[4];
    const float* Wih1 = (const float*)d_in[5];
    const float* Whh1 = (const float*)d_in[6];
    const float* bih1 = (const float*)d_in[7];
    const float* bhh1 = (const float*)d_in[8];
    const float* Wfc  = (const float*)d_in[9];
    const float* bfc  = (const float*)d_in[10];

    lstm_fused<<<256, 256, 0, stream>>>(x, Wih0, Whh0, bih0, bhh0,
                                        Wih1, Whh1, bih1, bhh1, Wfc, bfc,
                                        (float*)d_out, (char*)d_ws);
}